// Round 1
// baseline (2118.972 us; speedup 1.0000x reference)
//
#include <hip/hip_runtime.h>
#include <cmath>

// Decoder_spirals: fc -> (U2 upsample, spiralconv0+elu) -> (U1, conv1+elu) -> (U0, conv2)
// All fp32 (no fp32 MFMA on CDNA4 -> vector-ALU tiled GEMMs).
//
// Levels (incl dummy vertex): V0=11794 V1=2949 V2=738 V3=185
// SPIRAL = [20,14,12,9] (S3 unused), FILT = [128,128,64,3], B=16
//
// Workspace ping-pong:
//   bufA: max(x3 1.5MB, x2 6MB, x1 12MB)        = 12,079,104 B
//   bufB: max(x2u 6MB, x1u 24.2MB, x0u 48.3MB)  = 48,306,176 B

#define NB 16

// ---------------- FC: z(16,128) @ Wfc(128,23680) + bfc -> (16,185,128) ----------------
__global__ __launch_bounds__(256) void fc_kernel(const float* __restrict__ z,
                                                 const float* __restrict__ Wfc,
                                                 const float* __restrict__ bfc,
                                                 float* __restrict__ out) {
    const int N = 185 * 128;
    __shared__ float zs[NB * 128];
    int t = threadIdx.x;
    for (int i = t; i < NB * 128; i += 256) zs[i] = z[i];
    __syncthreads();
    int n = blockIdx.x * 256 + t;
    if (n >= N) return;
    float acc[NB];
#pragma unroll
    for (int b = 0; b < NB; ++b) acc[b] = 0.f;
    for (int k = 0; k < 128; ++k) {
        float w = Wfc[k * N + n];
#pragma unroll
        for (int b = 0; b < NB; ++b) acc[b] = fmaf(zs[b * 128 + k], w, acc[b]);
    }
    float bv = bfc[n];
#pragma unroll
    for (int b = 0; b < NB; ++b) out[(size_t)b * N + n] = acc[b] + bv;
}

// ------------- Upsample einsum: out[b,v,f] = sum_w U[v,w] * x[b,w,f] -------------
// GEMM: M=V rows (A=U row-major), N=16*F cols (B-operand = x viewed [w][(b,f)]), K=W.
// 64x64 tile, BK=16, 256 threads, 4x4 microtile.
__global__ __launch_bounds__(256) void upsample_kernel(const float* __restrict__ U,
                                                       const float* __restrict__ x,
                                                       float* __restrict__ out,
                                                       int V, int W, int Fshift) {
    const int F = 1 << Fshift;
    __shared__ float As[16][64];
    __shared__ float Bs[16][64];
    int t = threadIdx.x;
    int m0 = blockIdx.x * 64;
    int n0 = blockIdx.y * 64;

    int arow = t >> 2;            // 0..63
    int akk  = (t & 3) * 4;       // 0,4,8,12
    int bn   = t & 63;            // 0..63
    int bkk  = (t >> 6) * 4;      // 0,4,8,12

    int am = m0 + arow;
    bool arow_ok = (am < V);
    const float* Urow = U + (size_t)am * W;

    int ncol = n0 + bn;                 // n = b*F + f  (N = 16*F, multiple of 64)
    int bb = ncol >> Fshift;
    int ff = ncol & (F - 1);
    const float* xb = x + ((size_t)bb * W << Fshift) + ff;

    float acc[4][4];
#pragma unroll
    for (int i = 0; i < 4; ++i)
#pragma unroll
        for (int j = 0; j < 4; ++j) acc[i][j] = 0.f;

    int ty = t >> 4, tx = t & 15;

    for (int k0 = 0; k0 < W; k0 += 16) {
#pragma unroll
        for (int i = 0; i < 4; ++i) {
            int kk = akk + i;
            float v = 0.f;
            if (arow_ok && (k0 + kk) < W) v = Urow[k0 + kk];
            As[kk][arow] = v;
        }
#pragma unroll
        for (int i = 0; i < 4; ++i) {
            int kk = bkk + i;
            float v = 0.f;
            if ((k0 + kk) < W) v = xb[((size_t)(k0 + kk)) << Fshift];
            Bs[kk][bn] = v;
        }
        __syncthreads();
#pragma unroll
        for (int kk = 0; kk < 16; ++kk) {
            const float4 a4 = *reinterpret_cast<const float4*>(&As[kk][ty * 4]);
            const float4 b4 = *reinterpret_cast<const float4*>(&Bs[kk][tx * 4]);
            float av[4] = {a4.x, a4.y, a4.z, a4.w};
            float bv[4] = {b4.x, b4.y, b4.z, b4.w};
#pragma unroll
            for (int i = 0; i < 4; ++i)
#pragma unroll
                for (int j = 0; j < 4; ++j) acc[i][j] = fmaf(av[i], bv[j], acc[i][j]);
        }
        __syncthreads();
    }

#pragma unroll
    for (int i = 0; i < 4; ++i) {
        int m = m0 + ty * 4 + i;
        if (m >= V) continue;
#pragma unroll
        for (int j = 0; j < 4; ++j) {
            int n = n0 + tx * 4 + j;
            int b = n >> Fshift;
            int f = n & (F - 1);
            out[((size_t)b * V << Fshift) + ((size_t)m << Fshift) + f] = acc[i][j];
        }
    }
}

// ------- SpiralConv (Fout 128/64): gathered-A GEMM + bias + ELU + zero dummy -------
// M = 16*V (m = b*V+v), N = Fout, Kdim = K*Fin.  A[m,kk] = x[b, S[v, kk/Fin], kk%Fin]
__global__ __launch_bounds__(256) void spiral_gemm_kernel(const float* __restrict__ x,
                                                          const int* __restrict__ S,
                                                          const float* __restrict__ Wt,
                                                          const float* __restrict__ bias,
                                                          float* __restrict__ out,
                                                          int V, int K, int FinShift,
                                                          int Fout, int elu) {
    const int Fin = 1 << FinShift;
    const int Kdim = K << FinShift;
    const int M = NB * V;
    __shared__ float As[16][64];
    __shared__ float Bs[16][64];
    int t = threadIdx.x;
    int m0 = blockIdx.x * 64;
    int n0 = blockIdx.y * 64;

    int arow = t >> 2;
    int akk  = (t & 3) * 4;      // aligned to 4; stays within one spiral-k (Fin%16==0)
    int bn   = t & 63;
    int bkk  = (t >> 6) * 4;

    int am = m0 + arow;
    bool arow_ok = (am < M);
    int ab = 0, avtx = 0;
    if (arow_ok) { ab = am / V; avtx = am - ab * V; }
    const float* xbase = x + ((size_t)ab * V << FinShift);
    const int* Srow = S + (size_t)avtx * K;

    float acc[4][4];
#pragma unroll
    for (int i = 0; i < 4; ++i)
#pragma unroll
        for (int j = 0; j < 4; ++j) acc[i][j] = 0.f;

    int ty = t >> 4, tx = t & 15;

    for (int k0 = 0; k0 < Kdim; k0 += 16) {
        int kg = k0 + akk;
        float4 aval = make_float4(0.f, 0.f, 0.f, 0.f);
        if (arow_ok && kg < Kdim) {
            int ks = kg >> FinShift;
            int fi = kg & (Fin - 1);
            int idx = Srow[ks];
            aval = *reinterpret_cast<const float4*>(xbase + ((size_t)idx << FinShift) + fi);
        }
        As[akk + 0][arow] = aval.x;
        As[akk + 1][arow] = aval.y;
        As[akk + 2][arow] = aval.z;
        As[akk + 3][arow] = aval.w;
#pragma unroll
        for (int i = 0; i < 4; ++i) {
            int kk = bkk + i;
            float v = 0.f;
            if ((k0 + kk) < Kdim) v = Wt[(size_t)(k0 + kk) * Fout + n0 + bn];
            Bs[kk][bn] = v;
        }
        __syncthreads();
#pragma unroll
        for (int kk = 0; kk < 16; ++kk) {
            const float4 a4 = *reinterpret_cast<const float4*>(&As[kk][ty * 4]);
            const float4 b4 = *reinterpret_cast<const float4*>(&Bs[kk][tx * 4]);
            float av[4] = {a4.x, a4.y, a4.z, a4.w};
            float bv[4] = {b4.x, b4.y, b4.z, b4.w};
#pragma unroll
            for (int i = 0; i < 4; ++i)
#pragma unroll
                for (int j = 0; j < 4; ++j) acc[i][j] = fmaf(av[i], bv[j], acc[i][j]);
        }
        __syncthreads();
    }

#pragma unroll
    for (int i = 0; i < 4; ++i) {
        int m = m0 + ty * 4 + i;
        if (m >= M) continue;
        int b = m / V;
        int vv = m - b * V;
#pragma unroll
        for (int j = 0; j < 4; ++j) {
            int n = n0 + tx * 4 + j;
            float val = acc[i][j] + bias[n];
            if (elu) val = (val > 0.f) ? val : expm1f(val);
            if (vv == V - 1) val = 0.f;
            out[(size_t)m * Fout + n] = val;
        }
    }
}

// ------- Final conv (Fout=3, Fin=64, K=20): wave per (b,v), shuffle-reduce -------
__global__ __launch_bounds__(256) void spiral_out_kernel(const float* __restrict__ x,
                                                         const int* __restrict__ S,
                                                         const float* __restrict__ W,
                                                         const float* __restrict__ bias,
                                                         float* __restrict__ out,
                                                         int V) {
    __shared__ float Ws[20 * 64 * 3];
    int t = threadIdx.x;
    for (int i = t; i < 20 * 64 * 3; i += 256) Ws[i] = W[i];
    __syncthreads();

    int gw = (blockIdx.x * 256 + t) >> 6;   // global wave id = b*V + v
    int lane = t & 63;
    int total = NB * V;
    if (gw >= total) return;
    int b = gw / V;
    int v = gw - b * V;

    const float* xb = x + ((size_t)b * V) * 64 + lane;
    const int* Srow = S + (size_t)v * 20;
    float a0 = 0.f, a1 = 0.f, a2 = 0.f;
#pragma unroll
    for (int k = 0; k < 20; ++k) {
        int idx = Srow[k];
        float xv = xb[(size_t)idx * 64];
        const float* w = &Ws[(k * 64 + lane) * 3];
        a0 = fmaf(xv, w[0], a0);
        a1 = fmaf(xv, w[1], a1);
        a2 = fmaf(xv, w[2], a2);
    }
#pragma unroll
    for (int off = 32; off > 0; off >>= 1) {
        a0 += __shfl_down(a0, off);
        a1 += __shfl_down(a1, off);
        a2 += __shfl_down(a2, off);
    }
    if (lane == 0) {
        size_t o = (size_t)gw * 3;
        if (v == V - 1) {
            out[o] = 0.f; out[o + 1] = 0.f; out[o + 2] = 0.f;
        } else {
            out[o]     = a0 + bias[0];
            out[o + 1] = a1 + bias[1];
            out[o + 2] = a2 + bias[2];
        }
    }
}

extern "C" void kernel_launch(void* const* d_in, const int* in_sizes, int n_in,
                              void* d_out, int out_size, void* d_ws, size_t ws_size,
                              hipStream_t stream) {
    const float* z   = (const float*)d_in[0];
    const float* U0  = (const float*)d_in[1];
    const float* U1  = (const float*)d_in[2];
    const float* U2  = (const float*)d_in[3];
    const int*   S0  = (const int*)d_in[4];
    const int*   S1  = (const int*)d_in[5];
    const int*   S2  = (const int*)d_in[6];
    const float* Wfc = (const float*)d_in[7];
    const float* bfc = (const float*)d_in[8];
    const float* W0  = (const float*)d_in[9];
    const float* b0  = (const float*)d_in[10];
    const float* W1  = (const float*)d_in[11];
    const float* b1  = (const float*)d_in[12];
    const float* W2  = (const float*)d_in[13];
    const float* b2  = (const float*)d_in[14];
    float* out = (float*)d_out;

    char* ws = (char*)d_ws;
    float* bufA = (float*)ws;                   // holds x3 (1.5MB), x2 (6MB), x1 (12MB)
    float* bufB = (float*)(ws + 12079104);      // holds x2u (6MB), x1u (24.2MB), x0u (48.3MB)

    // 1. FC -> bufA : (16,185,128)
    fc_kernel<<<dim3((185 * 128 + 255) / 256), 256, 0, stream>>>(z, Wfc, bfc, bufA);
    // 2. U2 upsample -> bufB : (16,738,128)   V=738 W=185 F=128
    upsample_kernel<<<dim3((738 + 63) / 64, (NB * 128) / 64), 256, 0, stream>>>(
        U2, bufA, bufB, 738, 185, 7);
    // 3. conv0 (K=12, 128->128, elu) -> bufA : (16,738,128)
    spiral_gemm_kernel<<<dim3((NB * 738 + 63) / 64, 128 / 64), 256, 0, stream>>>(
        bufB, S2, W0, b0, bufA, 738, 12, 7, 128, 1);
    // 4. U1 upsample -> bufB : (16,2949,128)  V=2949 W=738 F=128
    upsample_kernel<<<dim3((2949 + 63) / 64, (NB * 128) / 64), 256, 0, stream>>>(
        U1, bufA, bufB, 2949, 738, 7);
    // 5. conv1 (K=14, 128->64, elu) -> bufA : (16,2949,64)
    spiral_gemm_kernel<<<dim3((NB * 2949 + 63) / 64, 64 / 64), 256, 0, stream>>>(
        bufB, S1, W1, b1, bufA, 2949, 14, 7, 64, 1);
    // 6. U0 upsample -> bufB : (16,11794,64)  V=11794 W=2949 F=64
    upsample_kernel<<<dim3((11794 + 63) / 64, (NB * 64) / 64), 256, 0, stream>>>(
        U0, bufA, bufB, 11794, 2949, 6);
    // 7. conv2 (K=20, 64->3, no act) -> d_out : (16,11794,3)
    int total_waves = NB * 11794;
    spiral_out_kernel<<<dim3(((size_t)total_waves * 64 + 255) / 256), 256, 0, stream>>>(
        bufB, S0, W2, b2, out, 11794);
}

// Round 2
// 1665.796 us; speedup vs baseline: 1.2720x; 1.2720x over previous
//
#include <hip/hip_runtime.h>
#include <cmath>

// Decoder_spirals: fc -> (U2 upsample, conv0+elu) -> (U1, conv1+elu) -> (U0, conv2)
// fp32 vector-ALU tiled GEMMs (no fp32 MFMA on CDNA4).
// R2: 128x128 tile / 8x8 microtile upsample, 128x64 / 8x4 conv, padded LDS (136)
// to kill the 4-way As-write bank conflicts seen in R1 (5.26e7/dispatch).

#define NB 16

// ---------------- FC: z(16,128) @ Wfc(128,23680) + bfc -> (16,185,128) ----------------
__global__ __launch_bounds__(256) void fc_kernel(const float* __restrict__ z,
                                                 const float* __restrict__ Wfc,
                                                 const float* __restrict__ bfc,
                                                 float* __restrict__ out) {
    const int N = 185 * 128;
    __shared__ float zs[NB * 128];
    int t = threadIdx.x;
    for (int i = t; i < NB * 128; i += 256) zs[i] = z[i];
    __syncthreads();
    int n = blockIdx.x * 256 + t;
    if (n >= N) return;
    float acc[NB];
#pragma unroll
    for (int b = 0; b < NB; ++b) acc[b] = 0.f;
    for (int k = 0; k < 128; ++k) {
        float w = Wfc[k * N + n];
#pragma unroll
        for (int b = 0; b < NB; ++b) acc[b] = fmaf(zs[b * 128 + k], w, acc[b]);
    }
    float bv = bfc[n];
#pragma unroll
    for (int b = 0; b < NB; ++b) out[(size_t)b * N + n] = acc[b] + bv;
}

// ------------- Upsample: out[b,v,f] = sum_w U[v,w] * x[b,w,f] -------------
// GEMM M=V (A=U), N=16*F (B = x as [w][(b,f)]), K=W.
// 128x128 tile, BK=16, 256 threads, 8x8 microtile (two 4-wide strips per dim).
__global__ __launch_bounds__(256) void upsample_kernel(const float* __restrict__ U,
                                                       const float* __restrict__ x,
                                                       float* __restrict__ out,
                                                       int V, int W, int Fshift) {
    const int F = 1 << Fshift;
    __shared__ float As[16][136];   // 136 = 128+8: stride 544B, 16B-aligned, 2-way max
    __shared__ float Bs[16][136];
    const int t = threadIdx.x;
    const int m0 = blockIdx.x * 128;
    const int n0 = blockIdx.y * 128;

    // A staging: thread -> row t>>1, k-chunk (t&1)*8 (8 scalars, transposed into As)
    const int arow = t >> 1;
    const int akk  = (t & 1) * 8;
    const int am = m0 + arow;
    const bool arow_ok = (am < V);
    const float* Urow = U + (size_t)am * W;

    // B staging: thread -> rows bkk, bkk+8, n-chunk (t&31)*4 (float4 from x)
    const int bkk = t >> 5;            // 0..7
    const int bn4 = (t & 31) * 4;
    const int ncol = n0 + bn4;
    const int bb = ncol >> Fshift;
    const int ff = ncol & (F - 1);
    const float* xb = x + (((size_t)bb * W) << Fshift) + ff;

    float acc[8][8];
#pragma unroll
    for (int i = 0; i < 8; ++i)
#pragma unroll
        for (int j = 0; j < 8; ++j) acc[i][j] = 0.f;

    const int ty = t >> 4, tx = t & 15;

    for (int k0 = 0; k0 < W; k0 += 16) {
        if (k0 + 16 <= W) {
#pragma unroll
            for (int i = 0; i < 8; ++i)
                As[akk + i][arow] = arow_ok ? Urow[k0 + akk + i] : 0.f;
        } else {
#pragma unroll
            for (int i = 0; i < 8; ++i) {
                int kk = akk + i;
                As[kk][arow] = (arow_ok && (k0 + kk) < W) ? Urow[k0 + kk] : 0.f;
            }
        }
        {
            float4 v0 = make_float4(0.f, 0.f, 0.f, 0.f);
            float4 v1 = v0;
            if (k0 + bkk < W)
                v0 = *reinterpret_cast<const float4*>(xb + (((size_t)(k0 + bkk)) << Fshift));
            if (k0 + bkk + 8 < W)
                v1 = *reinterpret_cast<const float4*>(xb + (((size_t)(k0 + bkk + 8)) << Fshift));
            *reinterpret_cast<float4*>(&Bs[bkk][bn4]) = v0;
            *reinterpret_cast<float4*>(&Bs[bkk + 8][bn4]) = v1;
        }
        __syncthreads();
#pragma unroll
        for (int kk = 0; kk < 16; ++kk) {
            const float4 a0 = *reinterpret_cast<const float4*>(&As[kk][ty * 4]);
            const float4 a1 = *reinterpret_cast<const float4*>(&As[kk][64 + ty * 4]);
            const float4 b0 = *reinterpret_cast<const float4*>(&Bs[kk][tx * 4]);
            const float4 b1 = *reinterpret_cast<const float4*>(&Bs[kk][64 + tx * 4]);
            float av[8] = {a0.x, a0.y, a0.z, a0.w, a1.x, a1.y, a1.z, a1.w};
            float bv[8] = {b0.x, b0.y, b0.z, b0.w, b1.x, b1.y, b1.z, b1.w};
#pragma unroll
            for (int i = 0; i < 8; ++i)
#pragma unroll
                for (int j = 0; j < 8; ++j) acc[i][j] = fmaf(av[i], bv[j], acc[i][j]);
        }
        __syncthreads();
    }

#pragma unroll
    for (int i = 0; i < 8; ++i) {
        int m = m0 + ((i < 4) ? (ty * 4 + i) : (64 + ty * 4 + (i - 4)));
        if (m >= V) continue;
#pragma unroll
        for (int j = 0; j < 8; ++j) {
            int n = n0 + ((j < 4) ? (tx * 4 + j) : (64 + tx * 4 + (j - 4)));
            int b = n >> Fshift;
            int f = n & (F - 1);
            out[(((size_t)b * V) << Fshift) + (((size_t)m) << Fshift) + f] = acc[i][j];
        }
    }
}

// ------- SpiralConv (Fout 128/64): gathered-A GEMM + bias + ELU + zero dummy -------
// M = 16*V, N = Fout, Kdim = K*Fin (multiple of 16). 128x64 tile, 8x4 microtile.
__global__ __launch_bounds__(256) void spiral_gemm_kernel(const float* __restrict__ x,
                                                          const int* __restrict__ S,
                                                          const float* __restrict__ Wt,
                                                          const float* __restrict__ bias,
                                                          float* __restrict__ out,
                                                          int V, int K, int FinShift,
                                                          int Fout, int elu) {
    const int Fin = 1 << FinShift;
    const int Kdim = K << FinShift;
    const int M = NB * V;
    __shared__ float As[16][136];
    __shared__ float Bs[16][72];
    const int t = threadIdx.x;
    const int m0 = blockIdx.x * 128;
    const int n0 = blockIdx.y * 64;

    const int arow = t >> 1;
    const int akk  = (t & 1) * 8;     // within one spiral-k block (Fin >= 64)
    const int am = m0 + arow;
    const bool arow_ok = (am < M);
    int ab = 0, avtx = 0;
    if (arow_ok) { ab = am / V; avtx = am - ab * V; }
    const float* xbase = x + (((size_t)ab * V) << FinShift);
    const int* Srow = S + (size_t)avtx * K;

    const int bkk = t >> 4;           // 0..15
    const int bn4 = (t & 15) * 4;

    float acc[8][4];
#pragma unroll
    for (int i = 0; i < 8; ++i)
#pragma unroll
        for (int j = 0; j < 4; ++j) acc[i][j] = 0.f;

    const int ty = t >> 4, tx = t & 15;

    for (int k0 = 0; k0 < Kdim; k0 += 16) {
        {
            float4 v0 = make_float4(0.f, 0.f, 0.f, 0.f);
            float4 v1 = v0;
            if (arow_ok) {
                int kg = k0 + akk;
                int ks = kg >> FinShift;
                int fi = kg & (Fin - 1);
                const float* p = xbase + (((size_t)Srow[ks]) << FinShift) + fi;
                v0 = *reinterpret_cast<const float4*>(p);
                v1 = *reinterpret_cast<const float4*>(p + 4);
            }
            As[akk + 0][arow] = v0.x;
            As[akk + 1][arow] = v0.y;
            As[akk + 2][arow] = v0.z;
            As[akk + 3][arow] = v0.w;
            As[akk + 4][arow] = v1.x;
            As[akk + 5][arow] = v1.y;
            As[akk + 6][arow] = v1.z;
            As[akk + 7][arow] = v1.w;
        }
        *reinterpret_cast<float4*>(&Bs[bkk][bn4]) =
            *reinterpret_cast<const float4*>(Wt + (size_t)(k0 + bkk) * Fout + n0 + bn4);
        __syncthreads();
#pragma unroll
        for (int kk = 0; kk < 16; ++kk) {
            const float4 a0 = *reinterpret_cast<const float4*>(&As[kk][ty * 4]);
            const float4 a1 = *reinterpret_cast<const float4*>(&As[kk][64 + ty * 4]);
            const float4 b0 = *reinterpret_cast<const float4*>(&Bs[kk][tx * 4]);
            float av[8] = {a0.x, a0.y, a0.z, a0.w, a1.x, a1.y, a1.z, a1.w};
            float bv[4] = {b0.x, b0.y, b0.z, b0.w};
#pragma unroll
            for (int i = 0; i < 8; ++i)
#pragma unroll
                for (int j = 0; j < 4; ++j) acc[i][j] = fmaf(av[i], bv[j], acc[i][j]);
        }
        __syncthreads();
    }

#pragma unroll
    for (int i = 0; i < 8; ++i) {
        int m = m0 + ((i < 4) ? (ty * 4 + i) : (64 + ty * 4 + (i - 4)));
        if (m >= M) continue;
        int b = m / V;
        int vv = m - b * V;
#pragma unroll
        for (int j = 0; j < 4; ++j) {
            int n = n0 + tx * 4 + j;
            float val = acc[i][j] + bias[n];
            if (elu) val = (val > 0.f) ? val : expm1f(val);
            if (vv == V - 1) val = 0.f;
            out[(size_t)m * Fout + n] = val;
        }
    }
}

// ------- Final conv (Fout=3, Fin=64, K=20): wave per (b,v), shuffle-reduce -------
__global__ __launch_bounds__(256) void spiral_out_kernel(const float* __restrict__ x,
                                                         const int* __restrict__ S,
                                                         const float* __restrict__ W,
                                                         const float* __restrict__ bias,
                                                         float* __restrict__ out,
                                                         int V) {
    __shared__ float Ws[20 * 64 * 3];
    int t = threadIdx.x;
    for (int i = t; i < 20 * 64 * 3; i += 256) Ws[i] = W[i];
    __syncthreads();

    int gw = (blockIdx.x * 256 + t) >> 6;
    int lane = t & 63;
    int total = NB * V;
    if (gw >= total) return;
    int b = gw / V;
    int v = gw - b * V;

    const float* xb = x + ((size_t)b * V) * 64 + lane;
    const int* Srow = S + (size_t)v * 20;
    float a0 = 0.f, a1 = 0.f, a2 = 0.f;
#pragma unroll
    for (int k = 0; k < 20; ++k) {
        int idx = Srow[k];
        float xv = xb[(size_t)idx * 64];
        const float* w = &Ws[(k * 64 + lane) * 3];
        a0 = fmaf(xv, w[0], a0);
        a1 = fmaf(xv, w[1], a1);
        a2 = fmaf(xv, w[2], a2);
    }
#pragma unroll
    for (int off = 32; off > 0; off >>= 1) {
        a0 += __shfl_down(a0, off);
        a1 += __shfl_down(a1, off);
        a2 += __shfl_down(a2, off);
    }
    if (lane == 0) {
        size_t o = (size_t)gw * 3;
        if (v == V - 1) {
            out[o] = 0.f; out[o + 1] = 0.f; out[o + 2] = 0.f;
        } else {
            out[o]     = a0 + bias[0];
            out[o + 1] = a1 + bias[1];
            out[o + 2] = a2 + bias[2];
        }
    }
}

extern "C" void kernel_launch(void* const* d_in, const int* in_sizes, int n_in,
                              void* d_out, int out_size, void* d_ws, size_t ws_size,
                              hipStream_t stream) {
    const float* z   = (const float*)d_in[0];
    const float* U0  = (const float*)d_in[1];
    const float* U1  = (const float*)d_in[2];
    const float* U2  = (const float*)d_in[3];
    const int*   S0  = (const int*)d_in[4];
    const int*   S1  = (const int*)d_in[5];
    const int*   S2  = (const int*)d_in[6];
    const float* Wfc = (const float*)d_in[7];
    const float* bfc = (const float*)d_in[8];
    const float* W0  = (const float*)d_in[9];
    const float* b0  = (const float*)d_in[10];
    const float* W1  = (const float*)d_in[11];
    const float* b1  = (const float*)d_in[12];
    const float* W2  = (const float*)d_in[13];
    const float* b2  = (const float*)d_in[14];
    float* out = (float*)d_out;

    char* ws = (char*)d_ws;
    float* bufA = (float*)ws;                   // x3 (1.5MB), x2 (6MB), x1 (12MB)
    float* bufB = (float*)(ws + 12079104);      // x2u (6MB), x1u (24.2MB), x0u (48.3MB)

    // 1. FC -> bufA : (16,185,128)
    fc_kernel<<<dim3((185 * 128 + 255) / 256), 256, 0, stream>>>(z, Wfc, bfc, bufA);
    // 2. U2 upsample -> bufB : (16,738,128)   V=738 W=185 F=128, N=2048
    upsample_kernel<<<dim3((738 + 127) / 128, 2048 / 128), 256, 0, stream>>>(
        U2, bufA, bufB, 738, 185, 7);
    // 3. conv0 (K=12, 128->128, elu) -> bufA : (16,738,128)
    spiral_gemm_kernel<<<dim3((NB * 738 + 127) / 128, 128 / 64), 256, 0, stream>>>(
        bufB, S2, W0, b0, bufA, 738, 12, 7, 128, 1);
    // 4. U1 upsample -> bufB : (16,2949,128)  V=2949 W=738 F=128, N=2048
    upsample_kernel<<<dim3((2949 + 127) / 128, 2048 / 128), 256, 0, stream>>>(
        U1, bufA, bufB, 2949, 738, 7);
    // 5. conv1 (K=14, 128->64, elu) -> bufA : (16,2949,64)
    spiral_gemm_kernel<<<dim3((NB * 2949 + 127) / 128, 64 / 64), 256, 0, stream>>>(
        bufB, S1, W1, b1, bufA, 2949, 14, 7, 64, 1);
    // 6. U0 upsample -> bufB : (16,11794,64)  V=11794 W=2949 F=64, N=1024
    upsample_kernel<<<dim3((11794 + 127) / 128, 1024 / 128), 256, 0, stream>>>(
        U0, bufA, bufB, 11794, 2949, 6);
    // 7. conv2 (K=20, 64->3, no act) -> d_out : (16,11794,3)
    int total_waves = NB * 11794;
    spiral_out_kernel<<<dim3(((size_t)total_waves * 64 + 255) / 256), 256, 0, stream>>>(
        bufB, S0, W2, b2, out, 11794);
}

// Round 3
// 1298.828 us; speedup vs baseline: 1.6314x; 1.2825x over previous
//
#include <hip/hip_runtime.h>
#include <cmath>

// Decoder_spirals, R2: bf16 MFMA (16x16x32) for all mid GEMMs.
// Activations kept fp32 in global; fp32->bf16 RNE conversion at LDS staging.
// LDS tiles [row][k] padded to 40 bf16/row (80B stride -> 2-way bank max).
// Wave = 64x64 output (4x4 frags), 4 waves/block. Grid n-fast for L2 A-reuse.
// Fallback if absmax too big: bf16x3 split-precision, same structure.

#define NB 16
#define LROW 40

typedef __attribute__((ext_vector_type(8))) short bf16x8;
typedef __attribute__((ext_vector_type(4))) float f32x4;

__device__ __forceinline__ unsigned short f2bf(float x) {
    union { float f; unsigned u; } v; v.f = x;
    unsigned r = v.u + 0x7FFFu + ((v.u >> 16) & 1u);
    return (unsigned short)(r >> 16);
}

// ---------------- FC: z(16,128) @ Wfc(128,23680) + bfc -> (16,185,128), fp32 ----------------
__global__ __launch_bounds__(256) void fc_kernel(const float* __restrict__ z,
                                                 const float* __restrict__ Wfc,
                                                 const float* __restrict__ bfc,
                                                 float* __restrict__ out) {
    const int N = 185 * 128;
    __shared__ float zs[NB * 128];
    int t = threadIdx.x;
    for (int i = t; i < NB * 128; i += 256) zs[i] = z[i];
    __syncthreads();
    int n = blockIdx.x * 256 + t;
    if (n >= N) return;
    float acc[NB];
#pragma unroll
    for (int b = 0; b < NB; ++b) acc[b] = 0.f;
    for (int k = 0; k < 128; ++k) {
        float w = Wfc[k * N + n];
#pragma unroll
        for (int b = 0; b < NB; ++b) acc[b] = fmaf(zs[b * 128 + k], w, acc[b]);
    }
    float bv = bfc[n];
#pragma unroll
    for (int b = 0; b < NB; ++b) out[(size_t)b * N + n] = acc[b] + bv;
}

// ------------- Upsample: out[b,v,f] = sum_w U[v,w] * x[b,w,f]  (bf16 MFMA) -------------
// GEMM: A = U [V][W] (m=v,k=w), B[k][n] = x[b][k][f] with n=b*F+f, C -> out.
template<int BM, int BN, int WCOLS>
__global__ __launch_bounds__(256) void ups_mfma(const float* __restrict__ U,
                                                const float* __restrict__ x,
                                                float* __restrict__ out,
                                                int V, int W, int Fshift) {
    const int F = 1 << Fshift;
    __shared__ __align__(16) unsigned short As[BM * LROW];
    __shared__ __align__(16) unsigned short Bs[BN * LROW];
    const int t = threadIdx.x;
    const int m0 = blockIdx.y * BM;
    const int n0 = blockIdx.x * BN;
    const int wv = t >> 6, lane = t & 63;
    const int wrow = (wv / WCOLS) * 64;
    const int wcol = (wv % WCOLS) * 64;
    const int lr = lane & 15;
    const int lko = (lane >> 4) * 8;

    f32x4 acc[4][4];
#pragma unroll
    for (int i = 0; i < 4; ++i)
#pragma unroll
        for (int j = 0; j < 4; ++j) acc[i][j] = {0.f, 0.f, 0.f, 0.f};

    const int AUN = BM / 32;  // A-stage units per thread

    for (int k0 = 0; k0 < W; k0 += 32) {
        // ---- stage A: U rows (scalar loads: W not 4-aligned), bf16 into As[m][k] ----
#pragma unroll
        for (int i = 0; i < AUN; ++i) {
            int u = t + 256 * i;
            int m = u >> 3;
            int kq = (u & 7) * 4;
            int gm = m0 + m, gk = k0 + kq;
            ushort4 w4 = make_ushort4(0, 0, 0, 0);
            if (gm < V) {
                const float* p = U + (size_t)gm * W + gk;
#pragma unroll
                for (int j = 0; j < 4; ++j)
                    if (gk + j < W) ((unsigned short*)&w4)[j] = f2bf(p[j]);
            }
            *(ushort4*)&As[m * LROW + kq] = w4;
        }
        // ---- stage B: x[b][k][f] float4 loads, 4x4 transpose, Bs[n][k] ----
        if (t < 2 * BN) {
            int kq = t & 7;           // kq-fast: LDS writes 2-way max
            int nq = t >> 3;
            int n = n0 + nq * 4;
            int b = n >> Fshift, f = n & (F - 1);
            int gk = k0 + kq * 4;
            const float* src = x + (((size_t)b * W + gk) << Fshift) + f;
            float4 r[4];
#pragma unroll
            for (int j = 0; j < 4; ++j) {
                if (gk + j < W) r[j] = *(const float4*)(src + ((size_t)j << Fshift));
                else r[j] = make_float4(0.f, 0.f, 0.f, 0.f);
            }
#pragma unroll
            for (int c = 0; c < 4; ++c) {
                ushort4 w4 = make_ushort4(f2bf(((const float*)&r[0])[c]),
                                          f2bf(((const float*)&r[1])[c]),
                                          f2bf(((const float*)&r[2])[c]),
                                          f2bf(((const float*)&r[3])[c]));
                *(ushort4*)&Bs[(nq * 4 + c) * LROW + kq * 4] = w4;
            }
        }
        __syncthreads();
        // ---- MFMA: wave 64x64, 16 mfma per K-step ----
        bf16x8 af[4], bg[4];
#pragma unroll
        for (int mt = 0; mt < 4; ++mt)
            af[mt] = *(const bf16x8*)&As[(wrow + mt * 16 + lr) * LROW + lko];
#pragma unroll
        for (int nt = 0; nt < 4; ++nt)
            bg[nt] = *(const bf16x8*)&Bs[(wcol + nt * 16 + lr) * LROW + lko];
#pragma unroll
        for (int mt = 0; mt < 4; ++mt)
#pragma unroll
            for (int nt = 0; nt < 4; ++nt)
                acc[mt][nt] = __builtin_amdgcn_mfma_f32_16x16x32_bf16(
                    af[mt], bg[nt], acc[mt][nt], 0, 0, 0);
        __syncthreads();
    }

    // ---- epilogue: C row=(lane>>4)*4+j, col=lane&15 (m89-verified) ----
#pragma unroll
    for (int mt = 0; mt < 4; ++mt) {
        int rbase = m0 + wrow + mt * 16 + (lane >> 4) * 4;
#pragma unroll
        for (int nt = 0; nt < 4; ++nt) {
            int col = n0 + wcol + nt * 16 + lr;
            int b = col >> Fshift, f = col & (F - 1);
            float* op = out + (((size_t)b * V) << Fshift) + f;
#pragma unroll
            for (int j = 0; j < 4; ++j) {
                int m = rbase + j;
                if (m < V) op[(size_t)m << Fshift] = acc[mt][nt][j];
            }
        }
    }
}

// ------- SpiralConv (bf16 MFMA): gathered-A GEMM + bias + ELU + zero dummy -------
// M = 16*V, N = Fout (== BN, grid.x = 1), Kdim = K*Fin (multiple of 32).
template<int BM, int BN, int WCOLS>
__global__ __launch_bounds__(256) void conv_mfma(const float* __restrict__ x,
                                                 const int* __restrict__ S,
                                                 const float* __restrict__ Wt,
                                                 const float* __restrict__ bias,
                                                 float* __restrict__ out,
                                                 int V, int K, int FinShift, int Fout,
                                                 int elu) {
    const int Fin = 1 << FinShift;
    const int Kdim = K << FinShift;
    const int M = NB * V;
    __shared__ __align__(16) unsigned short As[BM * LROW];
    __shared__ __align__(16) unsigned short Bs[BN * LROW];
    const int t = threadIdx.x;
    const int m0 = blockIdx.y * BM;
    const int wv = t >> 6, lane = t & 63;
    const int wrow = (wv / WCOLS) * 64;
    const int wcol = (wv % WCOLS) * 64;
    const int lr = lane & 15;
    const int lko = (lane >> 4) * 8;

    const int AUN = BM / 32;
    const int* Srow[AUN];
    size_t xbase[AUN];
    bool aok[AUN];
    int akq[AUN];
#pragma unroll
    for (int i = 0; i < AUN; ++i) {
        int u = t + 256 * i;
        int m = u >> 3;
        akq[i] = (u & 7) * 4;
        int gm = m0 + m;
        aok[i] = gm < M;
        int b = 0, vv = 0;
        if (aok[i]) { b = gm / V; vv = gm - b * V; }
        Srow[i] = S + (size_t)vv * K;
        xbase[i] = ((size_t)b * V) << FinShift;
    }

    f32x4 acc[4][4];
#pragma unroll
    for (int i = 0; i < 4; ++i)
#pragma unroll
        for (int j = 0; j < 4; ++j) acc[i][j] = {0.f, 0.f, 0.f, 0.f};

    for (int k0 = 0; k0 < Kdim; k0 += 32) {
        // ---- stage A: gathered float4 (Fin mult of 32 -> no k-split within unit) ----
#pragma unroll
        for (int i = 0; i < AUN; ++i) {
            int u = t + 256 * i;
            int m = u >> 3;
            ushort4 w4 = make_ushort4(0, 0, 0, 0);
            if (aok[i]) {
                int kg = k0 + akq[i];
                int ks = kg >> FinShift;
                int fi = kg & (Fin - 1);
                int idx = Srow[i][ks];
                const float4 r = *(const float4*)(x + xbase[i] + (((size_t)idx) << FinShift) + fi);
                w4 = make_ushort4(f2bf(r.x), f2bf(r.y), f2bf(r.z), f2bf(r.w));
            }
            *(ushort4*)&As[m * LROW + akq[i]] = w4;
        }
        // ---- stage B: Wt[k][n] float4, 4x4 transpose, Bs[n][k] ----
        if (t < 2 * BN) {
            int kq = t & 7;
            int nq = t >> 3;
            int gk = k0 + kq * 4;
            const float* src = Wt + (size_t)gk * Fout + nq * 4;
            float4 r[4];
#pragma unroll
            for (int j = 0; j < 4; ++j)
                r[j] = *(const float4*)(src + (size_t)j * Fout);
#pragma unroll
            for (int c = 0; c < 4; ++c) {
                ushort4 w4 = make_ushort4(f2bf(((const float*)&r[0])[c]),
                                          f2bf(((const float*)&r[1])[c]),
                                          f2bf(((const float*)&r[2])[c]),
                                          f2bf(((const float*)&r[3])[c]));
                *(ushort4*)&Bs[(nq * 4 + c) * LROW + kq * 4] = w4;
            }
        }
        __syncthreads();
        bf16x8 af[4], bg[4];
#pragma unroll
        for (int mt = 0; mt < 4; ++mt)
            af[mt] = *(const bf16x8*)&As[(wrow + mt * 16 + lr) * LROW + lko];
#pragma unroll
        for (int nt = 0; nt < 4; ++nt)
            bg[nt] = *(const bf16x8*)&Bs[(wcol + nt * 16 + lr) * LROW + lko];
#pragma unroll
        for (int mt = 0; mt < 4; ++mt)
#pragma unroll
            for (int nt = 0; nt < 4; ++nt)
                acc[mt][nt] = __builtin_amdgcn_mfma_f32_16x16x32_bf16(
                    af[mt], bg[nt], acc[mt][nt], 0, 0, 0);
        __syncthreads();
    }

#pragma unroll
    for (int mt = 0; mt < 4; ++mt) {
#pragma unroll
        for (int nt = 0; nt < 4; ++nt) {
            int col = wcol + nt * 16 + lr;       // n0 == 0 (grid.x == 1)
            float bv = bias[col];
#pragma unroll
            for (int j = 0; j < 4; ++j) {
                int m = m0 + wrow + mt * 16 + (lane >> 4) * 4 + j;
                if (m < M) {
                    float val = acc[mt][nt][j] + bv;
                    if (elu) val = val > 0.f ? val : expm1f(val);
                    int b = m / V;
                    int vv = m - b * V;
                    if (vv == V - 1) val = 0.f;
                    out[(size_t)m * Fout + col] = val;
                }
            }
        }
    }
}

// ------- Final conv (Fout=3, Fin=64, K=20): fp32 wave-per-(b,v) shuffle-reduce -------
__global__ __launch_bounds__(256) void spiral_out_kernel(const float* __restrict__ x,
                                                         const int* __restrict__ S,
                                                         const float* __restrict__ W,
                                                         const float* __restrict__ bias,
                                                         float* __restrict__ out,
                                                         int V) {
    __shared__ float Ws[20 * 64 * 3];
    int t = threadIdx.x;
    for (int i = t; i < 20 * 64 * 3; i += 256) Ws[i] = W[i];
    __syncthreads();

    int gw = (blockIdx.x * 256 + t) >> 6;
    int lane = t & 63;
    int total = NB * V;
    if (gw >= total) return;
    int b = gw / V;
    int v = gw - b * V;

    const float* xb = x + ((size_t)b * V) * 64 + lane;
    const int* Srow = S + (size_t)v * 20;
    float a0 = 0.f, a1 = 0.f, a2 = 0.f;
#pragma unroll
    for (int k = 0; k < 20; ++k) {
        int idx = Srow[k];
        float xv = xb[(size_t)idx * 64];
        const float* w = &Ws[(k * 64 + lane) * 3];
        a0 = fmaf(xv, w[0], a0);
        a1 = fmaf(xv, w[1], a1);
        a2 = fmaf(xv, w[2], a2);
    }
#pragma unroll
    for (int off = 32; off > 0; off >>= 1) {
        a0 += __shfl_down(a0, off);
        a1 += __shfl_down(a1, off);
        a2 += __shfl_down(a2, off);
    }
    if (lane == 0) {
        size_t o = (size_t)gw * 3;
        if (v == V - 1) {
            out[o] = 0.f; out[o + 1] = 0.f; out[o + 2] = 0.f;
        } else {
            out[o]     = a0 + bias[0];
            out[o + 1] = a1 + bias[1];
            out[o + 2] = a2 + bias[2];
        }
    }
}

extern "C" void kernel_launch(void* const* d_in, const int* in_sizes, int n_in,
                              void* d_out, int out_size, void* d_ws, size_t ws_size,
                              hipStream_t stream) {
    const float* z   = (const float*)d_in[0];
    const float* U0  = (const float*)d_in[1];
    const float* U1  = (const float*)d_in[2];
    const float* U2  = (const float*)d_in[3];
    const int*   S0  = (const int*)d_in[4];
    const int*   S1  = (const int*)d_in[5];
    const int*   S2  = (const int*)d_in[6];
    const float* Wfc = (const float*)d_in[7];
    const float* bfc = (const float*)d_in[8];
    const float* W0  = (const float*)d_in[9];
    const float* b0  = (const float*)d_in[10];
    const float* W1  = (const float*)d_in[11];
    const float* b1  = (const float*)d_in[12];
    const float* W2  = (const float*)d_in[13];
    const float* b2  = (const float*)d_in[14];
    float* out = (float*)d_out;

    char* ws = (char*)d_ws;
    float* bufA = (float*)ws;                   // x3 (1.5MB), x2 (6MB), x1 (12MB)
    float* bufB = (float*)(ws + 12079104);      // x2u (6MB), x1u (24.2MB), x0u (48.3MB)

    // 1. FC -> bufA : (16,185,128)
    fc_kernel<<<dim3((185 * 128 + 255) / 256), 256, 0, stream>>>(z, Wfc, bfc, bufA);
    // 2. U2 upsample -> bufB : (16,738,128)   V=738 W=185 F=128, N=2048
    ups_mfma<128, 128, 2><<<dim3(16, 6), 256, 0, stream>>>(U2, bufA, bufB, 738, 185, 7);
    // 3. conv0 (K=12, 128->128, elu) -> bufA : (16,738,128), M=11808
    conv_mfma<128, 128, 2><<<dim3(1, 93), 256, 0, stream>>>(
        bufB, S2, W0, b0, bufA, 738, 12, 7, 128, 1);
    // 4. U1 upsample -> bufB : (16,2949,128)  V=2949 W=738 F=128, N=2048
    ups_mfma<128, 128, 2><<<dim3(16, 24), 256, 0, stream>>>(U1, bufA, bufB, 2949, 738, 7);
    // 5. conv1 (K=14, 128->64, elu) -> bufA : (16,2949,64), M=47184
    conv_mfma<256, 64, 1><<<dim3(1, 185), 256, 0, stream>>>(
        bufB, S1, W1, b1, bufA, 2949, 14, 7, 64, 1);
    // 6. U0 upsample -> bufB : (16,11794,64)  V=11794 W=2949 F=64, N=1024
    ups_mfma<128, 128, 2><<<dim3(8, 93), 256, 0, stream>>>(U0, bufA, bufB, 11794, 2949, 6);
    // 7. conv2 (K=20, 64->3, fp32) -> d_out : (16,11794,3)
    int total_waves = NB * 11794;
    spiral_out_kernel<<<dim3(((size_t)total_waves * 64 + 255) / 256), 256, 0, stream>>>(
        bufB, S0, W2, b2, out, 11794);
}

// Round 4
// 444.120 us; speedup vs baseline: 4.7712x; 2.9245x over previous
//
#include <hip/hip_runtime.h>
#include <cmath>

// Decoder_spirals R3: m97-style 2-phase bf16 MFMA pipeline.
// - activations bf16 in ws; conv outputs stored TRANSPOSED [b][f][v] so the next
//   upsample's B operand is k-contiguous -> global_load_lds (16B) staging.
// - A (U mats) read fp32 (scalar, odd row stride) -> cvt -> ds_write; masked tail only.
// - LDS [row][32] bf16, XOR slot swizzle (slot ^= row&3): gload linear dest +
//   pre-swizzled global src + swizzled frag reads (rule #21 both-sides).
// - double-buffered BK=32, loads issued before MFMA, LDS writes after, 1 barrier/step.
// - ups grids XCD-chunk swizzled; convs = 1-wave 64x64 blocks, S-idx prefetched.

#define NB 16

typedef __attribute__((ext_vector_type(8))) short bf16x8;
typedef __attribute__((ext_vector_type(4))) float f32x4;

__device__ __forceinline__ unsigned short f2bf(float x) {
    union { float f; unsigned u; } v; v.f = x;
    unsigned r = v.u + 0x7FFFu + ((v.u >> 16) & 1u);
    return (unsigned short)(r >> 16);
}
__device__ __forceinline__ float bff(unsigned short h) {
    union { unsigned u; float f; } c; c.u = ((unsigned)h) << 16; return c.f;
}
__device__ __forceinline__ void gload16(const void* src, void* dst) {
    __builtin_amdgcn_global_load_lds(
        (const __attribute__((address_space(1))) unsigned int*)src,
        (__attribute__((address_space(3))) unsigned int*)dst, 16, 0, 0);
}

// ---------------- tiny converters ----------------
__global__ __launch_bounds__(256) void cvt_wT(const float* __restrict__ w,
                                              unsigned short* __restrict__ wT,
                                              int K, int N, int total) {
    int id = blockIdx.x * 256 + threadIdx.x;
    if (id >= total) return;
    int n = id / K, k = id - n * K;
    wT[id] = f2bf(w[(size_t)k * N + n]);
}
__global__ __launch_bounds__(256) void cvt_sT(const int* __restrict__ S,
                                              int* __restrict__ ST,
                                              int V, int K, int total) {
    int id = blockIdx.x * 256 + threadIdx.x;
    if (id >= total) return;
    int k = id / V, v = id - k * V;
    ST[id] = S[(size_t)v * K + k];
}

// ---------------- FC: z(16,128)@Wfc(128,23680)+bfc -> x3T[b*128+f][192] bf16 ----------------
__global__ __launch_bounds__(256) void fc_kernel(const float* __restrict__ z,
                                                 const float* __restrict__ Wfc,
                                                 const float* __restrict__ bfc,
                                                 unsigned short* __restrict__ x3T) {
    const int N = 185 * 128;
    __shared__ float zs[NB * 128];
    int t = threadIdx.x;
    for (int i = t; i < NB * 128; i += 256) zs[i] = z[i];
    __syncthreads();
    int n = blockIdx.x * 256 + t;
    if (n >= N) return;
    float acc[NB];
#pragma unroll
    for (int b = 0; b < NB; ++b) acc[b] = 0.f;
    for (int k = 0; k < 128; ++k) {
        float w = Wfc[k * N + n];
#pragma unroll
        for (int b = 0; b < NB; ++b) acc[b] = fmaf(zs[b * 128 + k], w, acc[b]);
    }
    float bv = bfc[n];
    int f = n & 127, v = n >> 7;
#pragma unroll
    for (int b = 0; b < NB; ++b)
        x3T[(size_t)(b * 128 + f) * 192 + v] = f2bf(acc[b] + bv);
}

// ------------- Upsample: out[b,v,f] = sum_w U[v,w]*x[b,w,f] -------------
// A = U fp32 [V][W] (reg-staged+cvt); B = xT bf16 [n=(b,f)][Wp] via global_load_lds.
// 128x128 tile, BK=32, dbuf, 4 waves of 64x64. out = bf16 [b][VP][F].
template<int FSH, int VP>
__global__ __launch_bounds__(256) void ups_mfma(
    const float* __restrict__ U, const unsigned short* __restrict__ xT,
    unsigned short* __restrict__ out,
    int V, int W, int Wp, int nsteps, int gxsh, int q) {
    const int F = 1 << FSH;
    __shared__ __align__(16) unsigned short As[2][128 * 32];
    __shared__ __align__(16) unsigned short Bs[2][128 * 32];
    const int t = threadIdx.x;
    const int wv = t >> 6, lane = t & 63;
    const int lr = lane & 15;

    // XCD-chunked bijective swizzle (nwg % 8 == 0)
    const int flat = blockIdx.x;
    const int wg = (flat & 7) * q + (flat >> 3);
    const int m0 = (wg >> gxsh) * 128;
    const int n0 = (wg & ((1 << gxsh) - 1)) * 128;

    // A staging: row ar = t>>1, element half ah = (t&1)*16
    const int ar = t >> 1;
    const int ah = (t & 1) * 16;
    const bool arok = (m0 + ar) < V;
    const float* Arow = U + (size_t)(m0 + ar) * W + ah;
    const int aw0 = ar * 32 + (((ah >> 3) + 0) ^ (ar & 3)) * 8;
    const int aw1 = ar * 32 + (((ah >> 3) + 1) ^ (ar & 3)) * 8;

    const int bswz = ((lane & 3) ^ ((lane >> 2) & 3)) * 8;  // src pre-swizzle
    const int fslot = ((lane >> 4) ^ (lr & 3)) * 8;          // frag read swizzle
    const int wrow = (wv >> 1) * 64;
    const int wcol = (wv & 1) * 64;

    float areg[16];
    f32x4 acc[4][4];
#pragma unroll
    for (int i = 0; i < 4; ++i)
#pragma unroll
        for (int j = 0; j < 4; ++j) acc[i][j] = {0.f, 0.f, 0.f, 0.f};

    // ---- prologue: stage step 0 into buf 0 (W >= 32 always here) ----
    {
        if (arok) {
#pragma unroll
            for (int j = 0; j < 16; ++j) areg[j] = Arow[j];
        } else {
#pragma unroll
            for (int j = 0; j < 16; ++j) areg[j] = 0.f;
        }
#pragma unroll
        for (int i = 0; i < 2; ++i) {
            const int ii = wv * 2 + i;
            const int n = n0 + ii * 16 + (lane >> 2);
            gload16(xT + (size_t)n * Wp + bswz, &Bs[0][ii * 512]);
        }
        bf16x8 w0, w1;
#pragma unroll
        for (int j = 0; j < 8; ++j) {
            w0[j] = (short)f2bf(areg[j]);
            w1[j] = (short)f2bf(areg[j + 8]);
        }
        *(bf16x8*)&As[0][aw0] = w0;
        *(bf16x8*)&As[0][aw1] = w1;
    }
    __syncthreads();

    for (int ts = 0; ts < nsteps; ++ts) {
        const int cur = ts & 1, nbuf = cur ^ 1, tn = ts + 1;
        const bool more = tn < nsteps;
        if (more) {
            const int k0 = tn * 32;
            if (k0 + 32 <= W) {
                if (arok) {
#pragma unroll
                    for (int j = 0; j < 16; ++j) areg[j] = Arow[k0 + j];
                } else {
#pragma unroll
                    for (int j = 0; j < 16; ++j) areg[j] = 0.f;
                }
            } else {
#pragma unroll
                for (int j = 0; j < 16; ++j)
                    areg[j] = (arok && (k0 + ah + j) < W) ? Arow[k0 + j] : 0.f;
            }
#pragma unroll
            for (int i = 0; i < 2; ++i) {
                const int ii = wv * 2 + i;
                const int n = n0 + ii * 16 + (lane >> 2);
                gload16(xT + (size_t)n * Wp + k0 + bswz, &Bs[nbuf][ii * 512]);
            }
        }
        bf16x8 af[4], bg[4];
#pragma unroll
        for (int mt = 0; mt < 4; ++mt)
            af[mt] = *(const bf16x8*)&As[cur][(wrow + mt * 16 + lr) * 32 + fslot];
#pragma unroll
        for (int nt = 0; nt < 4; ++nt)
            bg[nt] = *(const bf16x8*)&Bs[cur][(wcol + nt * 16 + lr) * 32 + fslot];
#pragma unroll
        for (int mt = 0; mt < 4; ++mt)
#pragma unroll
            for (int nt = 0; nt < 4; ++nt)
                acc[mt][nt] = __builtin_amdgcn_mfma_f32_16x16x32_bf16(
                    af[mt], bg[nt], acc[mt][nt], 0, 0, 0);
        if (more) {
            bf16x8 w0, w1;
#pragma unroll
            for (int j = 0; j < 8; ++j) {
                w0[j] = (short)f2bf(areg[j]);
                w1[j] = (short)f2bf(areg[j + 8]);
            }
            *(bf16x8*)&As[nbuf][aw0] = w0;
            *(bf16x8*)&As[nbuf][aw1] = w1;
        }
        __syncthreads();
    }

    // epilogue: C row=(lane>>4)*4+j (m), col=lane&15 (n); write bf16 [b][VP][F]
#pragma unroll
    for (int mt = 0; mt < 4; ++mt) {
        const int vb = m0 + wrow + mt * 16 + (lane >> 4) * 4;
#pragma unroll
        for (int nt = 0; nt < 4; ++nt) {
            const int col = n0 + wcol + nt * 16 + lr;
            const int b = col >> FSH, f = col & (F - 1);
            unsigned short* op = out + (size_t)b * VP * F + f;
#pragma unroll
            for (int j = 0; j < 4; ++j)
                op[(size_t)(vb + j) * F] = f2bf(acc[mt][nt][j]);
        }
    }
}

// ------- SpiralConv: gathered-A bf16 GEMM + bias + ELU + zero dummy, transposed out -------
// 1 wave, 64x64 tile, BK=32, dbuf. A: per-lane row gather (idx prefetched one slot ahead).
// B: WT[n][Kdim] via global_load_lds. out: x_T[(b*Fout+n)][VP] bf16.
template<int VP>
__global__ __launch_bounds__(64) void conv_mfma(
    const unsigned short* __restrict__ xu, const int* __restrict__ ST,
    const unsigned short* __restrict__ WT, const float* __restrict__ bias,
    unsigned short* __restrict__ outT,
    int VT, int Ksp, int Kdim, int nsteps, int Fout) {
    __shared__ __align__(16) unsigned short As[2][64 * 32];
    __shared__ __align__(16) unsigned short Bs[2][64 * 32];
    const int lane = threadIdx.x;
    const int lr = lane & 15;
    const int m0 = blockIdx.x * 64;
    const int n0 = blockIdx.y * 64;
    const int b = m0 / VP;
    const int v0 = m0 - b * VP;
    const unsigned short* xb = xu + (((size_t)b * VP) << 7);

    const int vg = (v0 + lane < VT) ? (v0 + lane) : (VT - 1);
    const int bswz = ((lane & 3) ^ ((lane >> 2) & 3)) * 8;
    const int fslot = ((lane >> 4) ^ (lr & 3)) * 8;
    int sw[4];
#pragma unroll
    for (int qq = 0; qq < 4; ++qq) sw[qq] = lane * 32 + ((qq ^ (lane & 3)) * 8);

    int s_c = 0;
    int idx_c = ST[vg];
    int idx_n = ST[(size_t)VT + vg];

    f32x4 acc[4][4];
#pragma unroll
    for (int i = 0; i < 4; ++i)
#pragma unroll
        for (int j = 0; j < 4; ++j) acc[i][j] = {0.f, 0.f, 0.f, 0.f};

    bf16x8 gr[4];
    // prologue: step 0 into buf 0
    {
        const unsigned short* p = xb + (((size_t)idx_c) << 7);
#pragma unroll
        for (int qq = 0; qq < 4; ++qq) gr[qq] = *(const bf16x8*)(p + qq * 8);
#pragma unroll
        for (int i = 0; i < 4; ++i) {
            const int n = n0 + i * 16 + (lane >> 2);
            gload16(WT + (size_t)n * Kdim + bswz, &Bs[0][i * 512]);
        }
#pragma unroll
        for (int qq = 0; qq < 4; ++qq) *(bf16x8*)&As[0][sw[qq]] = gr[qq];
    }
    __syncthreads();

    for (int ts = 0; ts < nsteps; ++ts) {
        const int cur = ts & 1, nbuf = cur ^ 1, tn = ts + 1;
        const bool more = tn < nsteps;
        if (more) {
            const int k0 = tn * 32;
            const int sn = k0 >> 7;
            const int idx = (sn != s_c) ? idx_n : idx_c;
            const unsigned short* p = xb + (((size_t)idx) << 7) + (k0 & 127);
#pragma unroll
            for (int qq = 0; qq < 4; ++qq) gr[qq] = *(const bf16x8*)(p + qq * 8);
#pragma unroll
            for (int i = 0; i < 4; ++i) {
                const int n = n0 + i * 16 + (lane >> 2);
                gload16(WT + (size_t)n * Kdim + k0 + bswz, &Bs[nbuf][i * 512]);
            }
            if (sn != s_c) {
                idx_c = idx_n;
                s_c = sn;
                if (s_c + 1 < Ksp) idx_n = ST[(size_t)(s_c + 1) * VT + vg];
            }
        }
        bf16x8 af[4], bg[4];
#pragma unroll
        for (int mt = 0; mt < 4; ++mt)
            af[mt] = *(const bf16x8*)&As[cur][(mt * 16 + lr) * 32 + fslot];
#pragma unroll
        for (int nt = 0; nt < 4; ++nt)
            bg[nt] = *(const bf16x8*)&Bs[cur][(nt * 16 + lr) * 32 + fslot];
#pragma unroll
        for (int mt = 0; mt < 4; ++mt)
#pragma unroll
            for (int nt = 0; nt < 4; ++nt)
                acc[mt][nt] = __builtin_amdgcn_mfma_f32_16x16x32_bf16(
                    af[mt], bg[nt], acc[mt][nt], 0, 0, 0);
        if (more) {
#pragma unroll
            for (int qq = 0; qq < 4; ++qq) *(bf16x8*)&As[nbuf][sw[qq]] = gr[qq];
        }
        __syncthreads();
    }

    // epilogue: bias + ELU + zero dummy, transposed bf16 store (j -> consecutive v)
#pragma unroll
    for (int nt = 0; nt < 4; ++nt) {
        const int n = n0 + nt * 16 + lr;
        const float bv = bias[n];
        unsigned short* op = outT + (size_t)(b * Fout + n) * VP;
#pragma unroll
        for (int mt = 0; mt < 4; ++mt) {
            const int v = v0 + mt * 16 + (lane >> 4) * 4;
            ushort4 stv;
#pragma unroll
            for (int j = 0; j < 4; ++j) {
                float val = acc[mt][nt][j] + bv;
                val = val > 0.f ? val : expm1f(val);
                if (v + j == VT - 1) val = 0.f;
                ((unsigned short*)&stv)[j] = f2bf(val);
            }
            *(ushort4*)(op + v) = stv;
        }
    }
}

// ------- Final conv (Fout=3, Fin=64, K=20): wave per (b,v), bf16 in, fp32 out -------
__global__ __launch_bounds__(256) void spiral_out_kernel(
    const unsigned short* __restrict__ x, const int* __restrict__ S,
    const float* __restrict__ W, const float* __restrict__ bias,
    float* __restrict__ out, int V, int VP) {
    __shared__ float Ws[20 * 64 * 3];
    int t = threadIdx.x;
    for (int i = t; i < 20 * 64 * 3; i += 256) Ws[i] = W[i];
    __syncthreads();

    int gw = (blockIdx.x * 256 + t) >> 6;
    int lane = t & 63;
    int total = NB * V;
    if (gw >= total) return;
    int b = gw / V;
    int v = gw - b * V;

    const unsigned short* xbp = x + ((size_t)b * VP) * 64 + lane;
    const int* Srow = S + (size_t)v * 20;
    float a0 = 0.f, a1 = 0.f, a2 = 0.f;
#pragma unroll
    for (int k = 0; k < 20; ++k) {
        int idx = Srow[k];
        float xv = bff(xbp[(size_t)idx * 64]);
        const float* w = &Ws[(k * 64 + lane) * 3];
        a0 = fmaf(xv, w[0], a0);
        a1 = fmaf(xv, w[1], a1);
        a2 = fmaf(xv, w[2], a2);
    }
#pragma unroll
    for (int off = 32; off > 0; off >>= 1) {
        a0 += __shfl_down(a0, off);
        a1 += __shfl_down(a1, off);
        a2 += __shfl_down(a2, off);
    }
    if (lane == 0) {
        size_t o = (size_t)gw * 3;
        if (v == V - 1) {
            out[o] = 0.f; out[o + 1] = 0.f; out[o + 2] = 0.f;
        } else {
            out[o]     = a0 + bias[0];
            out[o + 1] = a1 + bias[1];
            out[o + 2] = a2 + bias[2];
        }
    }
}

extern "C" void kernel_launch(void* const* d_in, const int* in_sizes, int n_in,
                              void* d_out, int out_size, void* d_ws, size_t ws_size,
                              hipStream_t stream) {
    const float* z   = (const float*)d_in[0];
    const float* U0  = (const float*)d_in[1];
    const float* U1  = (const float*)d_in[2];
    const float* U2  = (const float*)d_in[3];
    const int*   S0  = (const int*)d_in[4];
    const int*   S1  = (const int*)d_in[5];
    const int*   S2  = (const int*)d_in[6];
    const float* Wfc = (const float*)d_in[7];
    const float* bfc = (const float*)d_in[8];
    const float* W0  = (const float*)d_in[9];
    const float* b0  = (const float*)d_in[10];
    const float* W1  = (const float*)d_in[11];
    const float* b1  = (const float*)d_in[12];
    const float* W2  = (const float*)d_in[13];
    const float* b2  = (const float*)d_in[14];
    float* out = (float*)d_out;

    char* ws = (char*)d_ws;
    // bf16 activations (padded) + transposed weights/index tables, ~49.7 MiB total
    unsigned short* x3T = (unsigned short*)(ws + 0);         // [16*128][192]
    unsigned short* x2u = (unsigned short*)(ws + 786432);    // [16][768][128]
    unsigned short* x2T = (unsigned short*)(ws + 3932160);   // [16*128][768]
    unsigned short* x1u = (unsigned short*)(ws + 7077888);   // [16][3072][128]
    unsigned short* x1T = (unsigned short*)(ws + 19660800);  // [16*64][3072]
    unsigned short* x0u = (unsigned short*)(ws + 25952256);  // [16][11904][64]
    unsigned short* W0T = (unsigned short*)(ws + 50331648);  // [128][1536]
    unsigned short* W1T = (unsigned short*)(ws + 50724864);  // [64][1792]
    int* S0T = (int*)(ws + 50954240);                        // [20][11794]
    int* S1T = (int*)(ws + 51897760);                        // [14][2949]
    int* S2T = (int*)(ws + 52062904);                        // [12][738]

    // converters
    cvt_wT<<<dim3((128 * 1536 + 255) / 256), 256, 0, stream>>>(W0, W0T, 1536, 128, 128 * 1536);
    cvt_wT<<<dim3((64 * 1792 + 255) / 256), 256, 0, stream>>>(W1, W1T, 1792, 64, 64 * 1792);
    cvt_sT<<<dim3((20 * 11794 + 255) / 256), 256, 0, stream>>>(S0, S0T, 11794, 20, 20 * 11794);
    cvt_sT<<<dim3((14 * 2949 + 255) / 256), 256, 0, stream>>>(S1, S1T, 2949, 14, 14 * 2949);
    cvt_sT<<<dim3((12 * 738 + 255) / 256), 256, 0, stream>>>(S2, S2T, 738, 12, 12 * 738);

    // 1. FC -> x3T
    fc_kernel<<<dim3((185 * 128 + 255) / 256), 256, 0, stream>>>(z, Wfc, bfc, x3T);
    // 2. U2 upsample -> x2u : V=738 W=185 Wp=192, grid 6*16=96
    ups_mfma<7, 768><<<dim3(96), 256, 0, stream>>>(U2, x3T, x2u, 738, 185, 192, 6, 4, 12);
    // 3. conv0 (K=12,128->128,elu) -> x2T : M=16*768, grid (192,2)
    conv_mfma<768><<<dim3(192, 2), 64, 0, stream>>>(x2u, S2T, W0T, b0, x2T, 738, 12, 1536, 48, 128);
    // 4. U1 upsample -> x1u : V=2949 W=738 Wp=768, grid 24*16=384
    ups_mfma<7, 3072><<<dim3(384), 256, 0, stream>>>(U1, x2T, x1u, 2949, 738, 768, 24, 4, 48);
    // 5. conv1 (K=14,128->64,elu) -> x1T : M=16*3072, grid (768,1)
    conv_mfma<3072><<<dim3(768, 1), 64, 0, stream>>>(x1u, S1T, W1T, b1, x1T, 2949, 14, 1792, 56, 64);
    // 6. U0 upsample -> x0u : V=11794 W=2949 Wp=3072, grid 93*8=744
    ups_mfma<6, 11904><<<dim3(744), 256, 0, stream>>>(U0, x1T, x0u, 11794, 2949, 3072, 93, 3, 93);
    // 7. conv2 (K=20, 64->3, fp32 out) -> d_out
    spiral_out_kernel<<<dim3((NB * 11794 * 64 + 255) / 256), 256, 0, stream>>>(
        x0u, S0, W2, b2, out, 11794, 11904);
}